// Round 1
// baseline (3122.581 us; speedup 1.0000x reference)
//
#include <hip/hip_runtime.h>
#include <cfloat>
#include <cmath>

#define NB 512
#define NT 32
#define FIN 4096
#define NL 256
#define ND 256
#define NM (NB*NT)        // 16384
#define KCONV (3*FIN)     // 12288
#define SEGLD 288         // padded seg_in leading dim (257 -> 288)

#define BM 128
#define BN 128
#define BK 32
#define LDT 132           // padded LDS tile stride (float4-aligned)

__device__ __forceinline__ float nan0(float v) {
  if (__builtin_isnan(v)) return 0.0f;
  if (__builtin_isinf(v)) return v > 0.0f ? FLT_MAX : -FLT_MAX;
  return v;
}
__device__ __forceinline__ float sigmoidf_(float v) { return 1.0f / (1.0f + expf(-v)); }

// ---------------- repack conv weights: wt[(k*FIN+f)*NL + l] = w[l*KCONV + f*3 + k]
__global__ void __launch_bounds__(256) repack_w_k(const float* __restrict__ w,
                                                  float* __restrict__ wt) {
  int idx = blockIdx.x * 256 + threadIdx.x;   // over NL*KCONV = 3,145,728
  int l = idx / KCONV;
  int r = idx - l * KCONV;
  int f = r / 3;
  int k = r - f * 3;
  wt[(size_t)(k * FIN + f) * NL + l] = w[idx];
}

// ---------------- conv as fused GEMM: feature[m][l] = sum_kk A[m][kk]*Wt[kk][l] + bias[l]
// kk = k*4096+f ; A[m][kk] = valid ? x[(m+k-1)*FIN + f] : 0
__global__ void __launch_bounds__(256) conv_gemm_k(const float* __restrict__ x,
    const float* __restrict__ wt, const float* __restrict__ bias,
    float* __restrict__ feat) {
  __shared__ float As[BK][LDT];
  __shared__ float Bs[BK][LDT];
  const int tid = threadIdx.x;
  const int m0 = blockIdx.x * BM;
  const int n0 = blockIdx.y * BN;
  const int row0 = (tid >> 4) << 3;
  const int col0 = (tid & 15) << 3;
  float acc[8][8] = {};
  for (int it = 0; it < KCONV / BK; ++it) {
    const int kk0 = it * BK;
    const int ks = kk0 >> 12;       // conv tap 0..2 (constant within tile: 32 | 4096)
    const int f0 = kk0 & 4095;
#pragma unroll
    for (int i = 0; i < 4; ++i) {
      int v = i * 256 + tid;
      int row = v >> 3;
      int f4 = (v & 7) << 2;
      int m = m0 + row;
      int tt = (m & 31) + ks - 1;
      float4 val = make_float4(0.f, 0.f, 0.f, 0.f);
      if ((unsigned)tt < 32u) {
        val = *reinterpret_cast<const float4*>(x + (size_t)(m + ks - 1) * FIN + f0 + f4);
        val.x = nan0(val.x); val.y = nan0(val.y); val.z = nan0(val.z); val.w = nan0(val.w);
      }
      As[f4 + 0][row] = val.x;
      As[f4 + 1][row] = val.y;
      As[f4 + 2][row] = val.z;
      As[f4 + 3][row] = val.w;
    }
#pragma unroll
    for (int i = 0; i < 4; ++i) {
      int v = i * 256 + tid;
      int kr = v >> 5;
      int l4 = (v & 31) << 2;
      float4 bv = *reinterpret_cast<const float4*>(wt + (size_t)(kk0 + kr) * NL + n0 + l4);
      *reinterpret_cast<float4*>(&Bs[kr][l4]) = bv;
    }
    __syncthreads();
#pragma unroll
    for (int kk = 0; kk < BK; ++kk) {
      float a[8], b[8];
      *reinterpret_cast<float4*>(&a[0]) = *reinterpret_cast<const float4*>(&As[kk][row0]);
      *reinterpret_cast<float4*>(&a[4]) = *reinterpret_cast<const float4*>(&As[kk][row0 + 4]);
      *reinterpret_cast<float4*>(&b[0]) = *reinterpret_cast<const float4*>(&Bs[kk][col0]);
      *reinterpret_cast<float4*>(&b[4]) = *reinterpret_cast<const float4*>(&Bs[kk][col0 + 4]);
#pragma unroll
      for (int r = 0; r < 8; ++r)
#pragma unroll
        for (int c = 0; c < 8; ++c)
          acc[r][c] = fmaf(a[r], b[c], acc[r][c]);
    }
    __syncthreads();
  }
#pragma unroll
  for (int r = 0; r < 8; ++r) {
    int m = m0 + row0 + r;
#pragma unroll
    for (int c = 0; c < 8; ++c) {
      int n = n0 + col0 + c;
      feat[(size_t)m * NL + n] = acc[r][c] + bias[n];
    }
  }
}

// ---------------- generic C[M x N] = act(A[M x lda] @ W[N x ldw]^T + bias), ldc = N
// ACT: 0 = none, 1 = relu.  KB = valid K columns of W (cols >= KB read as 0).
template <int ACT>
__global__ void __launch_bounds__(256) gemm_wt_k(const float* __restrict__ A, int lda,
    const float* __restrict__ W, int ldw, int KB,
    const float* __restrict__ bias, float* __restrict__ C,
    int N, int K) {
  __shared__ float As[BK][LDT];
  __shared__ float Bs[BK][LDT];
  const int tid = threadIdx.x;
  const int m0 = blockIdx.x * BM;
  const int n0 = blockIdx.y * BN;
  const int row0 = (tid >> 4) << 3;
  const int col0 = (tid & 15) << 3;
  float acc[8][8] = {};
  for (int kk0 = 0; kk0 < K; kk0 += BK) {
#pragma unroll
    for (int i = 0; i < 4; ++i) {
      int v = i * 256 + tid;
      int row = v >> 3;
      int f4 = (v & 7) << 2;
      float4 val = *reinterpret_cast<const float4*>(A + (size_t)(m0 + row) * lda + kk0 + f4);
      As[f4 + 0][row] = val.x;
      As[f4 + 1][row] = val.y;
      As[f4 + 2][row] = val.z;
      As[f4 + 3][row] = val.w;
    }
#pragma unroll
    for (int i = 0; i < 4; ++i) {
      int v = i * 256 + tid;
      int n = v >> 3;
      int kq = (v & 7) << 2;
      int gn = n0 + n;
#pragma unroll
      for (int j = 0; j < 4; ++j) {
        int kk = kk0 + kq + j;
        float bv = 0.f;
        if (gn < N && kk < KB) bv = W[(size_t)gn * ldw + kk];
        Bs[kq + j][n] = bv;
      }
    }
    __syncthreads();
#pragma unroll
    for (int kk = 0; kk < BK; ++kk) {
      float a[8], b[8];
      *reinterpret_cast<float4*>(&a[0]) = *reinterpret_cast<const float4*>(&As[kk][row0]);
      *reinterpret_cast<float4*>(&a[4]) = *reinterpret_cast<const float4*>(&As[kk][row0 + 4]);
      *reinterpret_cast<float4*>(&b[0]) = *reinterpret_cast<const float4*>(&Bs[kk][col0]);
      *reinterpret_cast<float4*>(&b[4]) = *reinterpret_cast<const float4*>(&Bs[kk][col0 + 4]);
#pragma unroll
      for (int r = 0; r < 8; ++r)
#pragma unroll
        for (int c = 0; c < 8; ++c)
          acc[r][c] = fmaf(a[r], b[c], acc[r][c]);
    }
    __syncthreads();
  }
#pragma unroll
  for (int r = 0; r < 8; ++r) {
    int m = m0 + row0 + r;
#pragma unroll
    for (int c = 0; c < 8; ++c) {
      int n = n0 + col0 + c;
      if (n < N) {
        float v = acc[r][c] + bias[n];
        if (ACT == 1) v = fmaxf(v, 0.f);
        C[(size_t)m * (size_t)N + n] = v;
      }
    }
  }
}

// ---------------- gate: A[m] = gate_b + sum_d tanh(Yv)*sigmoid(Yu)*gw[d]; writes Aws and At
__global__ void __launch_bounds__(256) gate_k(const float* __restrict__ Yv,
    const float* __restrict__ Yu, const float* __restrict__ gw,
    const float* __restrict__ gb, float* __restrict__ Aws, float* __restrict__ At) {
  int lane = threadIdx.x & 63;
  int m = blockIdx.x * 4 + (threadIdx.x >> 6);
  float4 v4 = *reinterpret_cast<const float4*>(Yv + (size_t)m * ND + lane * 4);
  float4 u4 = *reinterpret_cast<const float4*>(Yu + (size_t)m * ND + lane * 4);
  float4 g4 = *reinterpret_cast<const float4*>(gw + lane * 4);
  float s = tanhf(v4.x) * sigmoidf_(u4.x) * g4.x
          + tanhf(v4.y) * sigmoidf_(u4.y) * g4.y
          + tanhf(v4.z) * sigmoidf_(u4.z) * g4.z
          + tanhf(v4.w) * sigmoidf_(u4.w) * g4.w;
#pragma unroll
  for (int off = 32; off > 0; off >>= 1) s += __shfl_xor(s, off, 64);
  if (lane == 0) {
    float a = s + gb[0];
    Aws[m] = a;
    At[m] = a;
  }
}

// ---------------- softmax over T then bag[b][l] = sum_t p_t feature[b][t][l]
__global__ void __launch_bounds__(256) softmax_bag_k(const float* __restrict__ Aws,
    const float* __restrict__ feat, float* __restrict__ bag) {
  __shared__ float av[NT];
  __shared__ float ev[NT];
  int b = blockIdx.x, tid = threadIdx.x;
  if (tid < NT) av[tid] = Aws[b * NT + tid];
  __syncthreads();
  float mx = -FLT_MAX;
#pragma unroll
  for (int t = 0; t < NT; ++t) mx = fmaxf(mx, av[t]);
  if (tid < NT) ev[tid] = expf(av[tid] - mx);
  __syncthreads();
  float ssum = 0.f;
#pragma unroll
  for (int t = 0; t < NT; ++t) ssum += ev[t];
  float accv = 0.f;
#pragma unroll
  for (int t = 0; t < NT; ++t) accv += ev[t] * feat[((size_t)b * NT + t) * NL + tid];
  bag[(size_t)b * NL + tid] = accv / ssum;
}

// ---------------- final 32->1 layer + sigmoid (+scale), strided output
__global__ void __launch_bounds__(256) rowdot32_k(const float* __restrict__ H,
    const float* __restrict__ w, const float* __restrict__ bptr,
    float* __restrict__ outp, int ostride, float scale) {
  int m = blockIdx.x * 256 + threadIdx.x;
  const float* h = H + (size_t)m * 32;
  float s = bptr[0];
#pragma unroll
  for (int i = 0; i < 32; i += 4) {
    float4 hv = *reinterpret_cast<const float4*>(h + i);
    float4 wv = *reinterpret_cast<const float4*>(w + i);
    s += hv.x * wv.x + hv.y * wv.y + hv.z * wv.z + hv.w * wv.w;
  }
  outp[(size_t)m * ostride] = scale * sigmoidf_(s);
}

// ---------------- seg_in = [feature | A | zero-pad] with row stride 288
__global__ void __launch_bounds__(64) make_segin_k(const float* __restrict__ feat,
    const float* __restrict__ Aws, float* __restrict__ segin) {
  int m = blockIdx.x, lane = threadIdx.x;
  float4 v = *reinterpret_cast<const float4*>(feat + (size_t)m * NL + lane * 4);
  *reinterpret_cast<float4*>(segin + (size_t)m * SEGLD + lane * 4) = v;
  if (lane == 0) segin[(size_t)m * SEGLD + 256] = Aws[m];
  if (lane >= 1 && lane < 32) segin[(size_t)m * SEGLD + 256 + lane] = 0.f;
}

// ---------------- per-sample 2-means cosine (100 iters), one wave per sample.
// Writes assigns (as float 0/1) and output[b*2+1] = 0.5*max(m0,m1).
__global__ void __launch_bounds__(64) kmeans_k(const float* __restrict__ feat,
    const float* __restrict__ seg, float* __restrict__ assigns_out,
    float* __restrict__ outpair) {
  __shared__ float fls[NT][260];
  int b = blockIdx.x, lane = threadIdx.x;
  int l0 = lane << 2;
  float fn[NT][4];                 // normalized rows, lane's 4-l slice
  // load raw f into LDS; compute row norms via wave allreduce; build fn
#pragma unroll
  for (int t = 0; t < NT; ++t) {
    float4 v = *reinterpret_cast<const float4*>(feat + ((size_t)b * NT + t) * NL + l0);
    *reinterpret_cast<float4*>(&fls[t][l0]) = v;
    float ss = v.x * v.x + v.y * v.y + v.z * v.z + v.w * v.w;
#pragma unroll
    for (int off = 32; off > 0; off >>= 1) ss += __shfl_xor(ss, off, 64);
    float nr = sqrtf(ss) + 1e-8f;
    fn[t][0] = v.x / nr; fn[t][1] = v.y / nr; fn[t][2] = v.z / nr; fn[t][3] = v.w / nr;
  }
  __syncthreads();
  float cr0[4], cr1[4];
#pragma unroll
  for (int i = 0; i < 4; ++i) { cr0[i] = fls[0][l0 + i]; cr1[i] = fls[16][l0 + i]; }

  unsigned long long amask = 0ull;
  int c1n = 0;
  for (int it = 0; it < 100; ++it) {
    // normalize centers (elementwise division like ref)
    float ss0 = cr0[0]*cr0[0] + cr0[1]*cr0[1] + cr0[2]*cr0[2] + cr0[3]*cr0[3];
    float ss1 = cr1[0]*cr1[0] + cr1[1]*cr1[1] + cr1[2]*cr1[2] + cr1[3]*cr1[3];
#pragma unroll
    for (int off = 32; off > 0; off >>= 1) {
      ss0 += __shfl_xor(ss0, off, 64);
      ss1 += __shfl_xor(ss1, off, 64);
    }
    float nr0 = sqrtf(ss0) + 1e-8f, nr1 = sqrtf(ss1) + 1e-8f;
    float cn0[4], cn1[4];
#pragma unroll
    for (int i = 0; i < 4; ++i) { cn0[i] = cr0[i] / nr0; cn1[i] = cr1[i] / nr1; }
    // partial sims, 64 values per lane (one per (t,j))
    float p[64];
#pragma unroll
    for (int t = 0; t < NT; ++t) {
      p[2*t]   = fn[t][0]*cn0[0] + fn[t][1]*cn0[1] + fn[t][2]*cn0[2] + fn[t][3]*cn0[3];
      p[2*t+1] = fn[t][0]*cn1[0] + fn[t][1]*cn1[1] + fn[t][2]*cn1[2] + fn[t][3]*cn1[3];
    }
    // recursive-halving cross-lane reduce: lane q ends with full sim for index q
    float v32[32];
    { bool hi = (lane & 32) != 0;
#pragma unroll
      for (int i = 0; i < 32; ++i) {
        float keep = hi ? p[32+i] : p[i];
        float send = hi ? p[i] : p[32+i];
        v32[i] = keep + __shfl_xor(send, 32, 64);
      } }
    float v16[16];
    { bool hi = (lane & 16) != 0;
#pragma unroll
      for (int i = 0; i < 16; ++i) {
        float keep = hi ? v32[16+i] : v32[i];
        float send = hi ? v32[i] : v32[16+i];
        v16[i] = keep + __shfl_xor(send, 16, 64);
      } }
    float v8[8];
    { bool hi = (lane & 8) != 0;
#pragma unroll
      for (int i = 0; i < 8; ++i) {
        float keep = hi ? v16[8+i] : v16[i];
        float send = hi ? v16[i] : v16[8+i];
        v8[i] = keep + __shfl_xor(send, 8, 64);
      } }
    float v4[4];
    { bool hi = (lane & 4) != 0;
#pragma unroll
      for (int i = 0; i < 4; ++i) {
        float keep = hi ? v8[4+i] : v8[i];
        float send = hi ? v8[i] : v8[4+i];
        v4[i] = keep + __shfl_xor(send, 4, 64);
      } }
    float v2[2];
    { bool hi = (lane & 2) != 0;
#pragma unroll
      for (int i = 0; i < 2; ++i) {
        float keep = hi ? v4[2+i] : v4[i];
        float send = hi ? v4[i] : v4[2+i];
        v2[i] = keep + __shfl_xor(send, 2, 64);
      } }
    float sim;
    { bool hi = (lane & 1) != 0;
      float keep = hi ? v2[1] : v2[0];
      float send = hi ? v2[0] : v2[1];
      sim = keep + __shfl_xor(send, 1, 64);
    }
    // lane 2t holds sim[t][0], lane 2t+1 holds sim[t][1]
    float simo = __shfl_xor(sim, 1, 64);
    bool is0 = (lane & 1) == 0;
    unsigned long long mask = __ballot(is0 && (simo > sim));  // argmax, ties -> 0
    int c1 = __popcll(mask);
    int c0 = NT - c1;
    // per-cluster sums of raw f (direct, sequential over t like ref)
    float s0v[4] = {0,0,0,0}, s1v[4] = {0,0,0,0};
#pragma unroll
    for (int t = 0; t < NT; ++t) {
      float4 fv = *reinterpret_cast<const float4*>(&fls[t][l0]);
      if (mask & (1ull << (2*t))) {
        s1v[0] += fv.x; s1v[1] += fv.y; s1v[2] += fv.z; s1v[3] += fv.w;
      } else {
        s0v[0] += fv.x; s0v[1] += fv.y; s0v[2] += fv.z; s0v[3] += fv.w;
      }
    }
    float fc0 = fmaxf((float)c0, 1.0f), fc1 = fmaxf((float)c1, 1.0f);
#pragma unroll
    for (int i = 0; i < 4; ++i) {
      float n0v = s0v[i] / fc0;
      float n1v = s1v[i] / fc1;
      cr0[i] = (c0 > 0) ? n0v : cr0[i];
      cr1[i] = (c1 > 0) ? n1v : cr1[i];
    }
    amask = mask; c1n = c1;
  }
  if (lane < NT)
    assigns_out[(size_t)b * NT + lane] = (amask & (1ull << (2*lane))) ? 1.0f : 0.0f;
  if (lane == 0) {
    float sum0 = 0.f, sum1 = 0.f;
    for (int t = 0; t < NT; ++t) {
      float sv = seg[(size_t)b * NT + t];
      if (amask & (1ull << (2*t))) sum1 += sv; else sum0 += sv;
    }
    int c1 = c1n, c0 = NT - c1n;
    float m0 = (c0 > 0) ? (sum0 / fmaxf((float)c0, 1.f)) : -INFINITY;
    float m1 = (c1 > 0) ? (sum1 / fmaxf((float)c1, 1.f)) : -INFINITY;
    outpair[(size_t)b * 2 + 1] = 0.5f * fmaxf(m0, m1);
  }
}

extern "C" void kernel_launch(void* const* d_in, const int* in_sizes, int n_in,
                              void* d_out, int out_size, void* d_ws, size_t ws_size,
                              hipStream_t stream) {
  const float* x      = (const float*)d_in[0];
  const float* tsn_w  = (const float*)d_in[1];
  const float* tsn_b  = (const float*)d_in[2];
  const float* aV_w   = (const float*)d_in[3];
  const float* aV_b   = (const float*)d_in[4];
  const float* aU_w   = (const float*)d_in[5];
  const float* aU_b   = (const float*)d_in[6];
  const float* gate_w = (const float*)d_in[7];
  const float* gate_b = (const float*)d_in[8];
  const float* cb_w0  = (const float*)d_in[9];
  const float* cb_b0  = (const float*)d_in[10];
  const float* cb_w1  = (const float*)d_in[11];
  const float* cb_b1  = (const float*)d_in[12];
  const float* cb_w2  = (const float*)d_in[13];
  const float* cb_b2  = (const float*)d_in[14];
  const float* cb_w3  = (const float*)d_in[15];
  const float* cb_b3  = (const float*)d_in[16];
  const float* cs_w0  = (const float*)d_in[17];
  const float* cs_b0  = (const float*)d_in[18];
  const float* cs_w1  = (const float*)d_in[19];
  const float* cs_b1  = (const float*)d_in[20];
  const float* cs_w2  = (const float*)d_in[21];
  const float* cs_b2  = (const float*)d_in[22];
  const float* cs_w3  = (const float*)d_in[23];
  const float* cs_b3  = (const float*)d_in[24];

  float* out = (float*)d_out;
  float* o_feat   = out;                 // 512*32*256 = 4,194,304
  float* o_assign = out + 4194304;       // 16,384
  float* o_seg    = out + 4210688;       // 16,384
  float* o_out    = out + 4227072;       // 1,024 (B x 2)
  float* o_At     = out + 4228096;       // 16,384

  char* ws = (char*)d_ws;
  // phase-overlapped workspace (peak ~37.1 MB)
  float* WT    = (float*)ws;                     // conv phase: 12.6 MB
  float* YV    = (float*)ws;                     // attn phase: 16.8 MB
  float* YU    = (float*)(ws + 16777216);        // 16.8 MB
  float* SEGIN = (float*)ws;                     // seg phase: 18.9 MB
  float* SH0   = (float*)(ws + 18874368);        // 16.8 MB  (ends 35,651,584)
  float* SH1   = (float*)ws;                     // 8.4 MB (over dead SEGIN)
  float* SH2   = (float*)(ws + 8388608);         // 2.1 MB
  float* AWS   = (float*)(ws + 35651584);        // 64 KB
  float* BAG   = (float*)(ws + 35717120);        // 512 KB
  float* BH0   = (float*)(ws + 36241408);        // 512 KB
  float* BH1   = (float*)(ws + 36765696);        // 256 KB
  float* BH2   = (float*)(ws + 37027840);        // 64 KB  (end 37,093,376)

  // 1) conv weight repack
  repack_w_k<<<dim3(12288), dim3(256), 0, stream>>>(tsn_w, WT);
  // 2) conv -> feature
  conv_gemm_k<<<dim3(128, 2), dim3(256), 0, stream>>>(x, WT, tsn_b, o_feat);
  // 3-4) attention projections
  gemm_wt_k<0><<<dim3(128, 2), dim3(256), 0, stream>>>(o_feat, 256, aV_w, 256, 256, aV_b, YV, 256, 256);
  gemm_wt_k<0><<<dim3(128, 2), dim3(256), 0, stream>>>(o_feat, 256, aU_w, 256, 256, aU_b, YU, 256, 256);
  // 5) gate -> A (ws) and At (out)
  gate_k<<<dim3(4096), dim3(256), 0, stream>>>(YV, YU, gate_w, gate_b, AWS, o_At);
  // 6) softmax over T + bag
  softmax_bag_k<<<dim3(512), dim3(256), 0, stream>>>(AWS, o_feat, BAG);
  // 7-10) bag classifier -> output[:,0]
  gemm_wt_k<1><<<dim3(4, 2), dim3(256), 0, stream>>>(BAG, 256, cb_w0, 256, 256, cb_b0, BH0, 256, 256);
  gemm_wt_k<1><<<dim3(4, 1), dim3(256), 0, stream>>>(BH0, 256, cb_w1, 256, 256, cb_b1, BH1, 128, 256);
  gemm_wt_k<1><<<dim3(4, 1), dim3(256), 0, stream>>>(BH1, 128, cb_w2, 128, 128, cb_b2, BH2, 32, 128);
  rowdot32_k<<<dim3(2), dim3(256), 0, stream>>>(BH2, cb_w3, cb_b3, o_out, 2, 0.5f);
  // 11) seg input concat (padded to 288, zeros beyond col 256)
  make_segin_k<<<dim3(16384), dim3(64), 0, stream>>>(o_feat, AWS, SEGIN);
  // 12-15) seg classifier -> output_seg
  gemm_wt_k<1><<<dim3(128, 2), dim3(256), 0, stream>>>(SEGIN, SEGLD, cs_w0, 257, 257, cs_b0, SH0, 256, SEGLD);
  gemm_wt_k<1><<<dim3(128, 1), dim3(256), 0, stream>>>(SH0, 256, cs_w1, 256, 256, cs_b1, SH1, 128, 256);
  gemm_wt_k<1><<<dim3(128, 1), dim3(256), 0, stream>>>(SH1, 128, cs_w2, 128, 128, cs_b2, SH2, 32, 128);
  rowdot32_k<<<dim3(64), dim3(256), 0, stream>>>(SH2, cs_w3, cs_b3, o_seg, 1, 1.0f);
  // 16) kmeans -> assigns + output[:,1]
  kmeans_k<<<dim3(512), dim3(64), 0, stream>>>(o_feat, o_seg, o_assign, o_out);
}

// Round 2
// 1233.520 us; speedup vs baseline: 2.5314x; 2.5314x over previous
//
#include <hip/hip_runtime.h>
#include <cfloat>
#include <cmath>

#define NB 512
#define NT 32
#define FIN 4096
#define NL 256
#define ND 256
#define NM (NB*NT)        // 16384
#define KCONV (3*FIN)     // 12288
#define SEGLD 288         // padded seg_in leading dim (257 -> 288)
#define PLANE 3145728     // ushorts per weight plane (12288*256)

#define BM 128
#define BN 128
#define BK 32
#define LDT 132           // padded LDS tile stride (float4-aligned)

typedef __attribute__((ext_vector_type(8))) short short8_t;
typedef __attribute__((ext_vector_type(4))) float f32x4;

__device__ __forceinline__ float sigmoidf_(float v) { return 1.0f / (1.0f + expf(-v)); }

__device__ __forceinline__ unsigned short f2bf(float v) {
  unsigned u = __float_as_uint(v);
  unsigned r = u + 0x7FFFu + ((u >> 16) & 1u);
  return (unsigned short)(r >> 16);
}
__device__ __forceinline__ float bf2f(unsigned short h) {
  return __uint_as_float(((unsigned)h) << 16);
}

// ---------------- repack conv weights into MFMA-fragment-linear hi/lo bf16 planes.
// dest d = ((kt*16 + bc)*64 + lane)*8 + j ; kb=lane>>4 ; kk=kt*32+kb*8+j ; l=bc*16+(lane&15)
// src  = w[l*12288 + f*3 + tap], kk = tap*4096 + f
__global__ void __launch_bounds__(256) repack_frag_k(const float* __restrict__ w,
                                                     unsigned short* __restrict__ wt) {
  int d = blockIdx.x * 256 + threadIdx.x;   // over 3,145,728
  int kt = d >> 13;
  int bc = (d >> 9) & 15;
  int lane = (d >> 3) & 63;
  int j = d & 7;
  int kb = lane >> 4;
  int kk = kt * 32 + kb * 8 + j;
  int l = bc * 16 + (lane & 15);
  int tap = kk >> 12;
  int f = kk & 4095;
  float v = w[(size_t)l * KCONV + f * 3 + tap];
  unsigned short hi = f2bf(v);
  unsigned short lo = f2bf(v - bf2f(hi));
  wt[d] = hi;
  wt[PLANE + d] = lo;
}

// ---------------- conv as bf16x3 MFMA GEMM, split-K=2, 128x128 tile, 4 waves.
// PART[ks][m][l] partial sums (no bias).
__global__ void __launch_bounds__(256) conv_mfma_k(const float* __restrict__ x,
    const unsigned short* __restrict__ WT, float* __restrict__ PART) {
  __shared__ __align__(16) unsigned short AS[8192];  // [plane][br0..7][lane][j]
  __shared__ __align__(16) unsigned short BS[8192];  // [plane][bc0..7][lane][j]
  const int tid = threadIdx.x;
  const int m0 = blockIdx.x * 128;
  const int by = blockIdx.y;
  const int ktBase = blockIdx.z * 192;
  const int lane = tid & 63;
  const int w = tid >> 6, wr = w >> 1, wc = w & 1;
  const int kb = tid & 3;
  const int rquot = tid >> 2;       // 0..63

  f32x4 acc[4][4] = {};
  float4 avreg[4];
  short8_t bvreg[4];

  // ---- prologue load (tile ktBase)
  {
    int ktg = ktBase;
    int tap = ktg >> 7;
    int f0 = (ktg & 127) << 5;
#pragma unroll
    for (int u = 0; u < 2; ++u) {
      int row = u * 64 + rquot;
      int gm = m0 + row;
      int tt = (gm & 31) + tap - 1;
      if ((unsigned)tt < 32u) {
        const float* src = x + (size_t)(gm + tap - 1) * FIN + f0 + kb * 8;
        avreg[u*2+0] = *reinterpret_cast<const float4*>(src);
        avreg[u*2+1] = *reinterpret_cast<const float4*>(src + 4);
      } else {
        avreg[u*2+0] = make_float4(0,0,0,0);
        avreg[u*2+1] = make_float4(0,0,0,0);
      }
    }
    const unsigned short* bsrc = WT + ((size_t)ktg * 16 + by * 8) * 512;
#pragma unroll
    for (int q = 0; q < 4; ++q) {
      int p = q >> 1, pass = q & 1;
      bvreg[q] = *reinterpret_cast<const short8_t*>(bsrc + (size_t)p * PLANE + (pass*256 + tid) * 8);
    }
  }

  for (int i = 0; i < 192; ++i) {
    // ---- write staged regs -> LDS (convert A to hi/lo bf16)
#pragma unroll
    for (int u = 0; u < 2; ++u) {
      float vv[8];
      *reinterpret_cast<float4*>(&vv[0]) = avreg[u*2+0];
      *reinterpret_cast<float4*>(&vv[4]) = avreg[u*2+1];
      __align__(16) unsigned short hi[8];
      __align__(16) unsigned short lo[8];
#pragma unroll
      for (int e = 0; e < 8; ++e) {
        float v = vv[e];
        v = (v == v) ? v : 0.0f;
        unsigned short h = f2bf(v);
        hi[e] = h;
        lo[e] = f2bf(v - bf2f(h));
      }
      int row = u * 64 + rquot;
      int br = row >> 4;
      int lanew = (row & 15) + (kb << 4);
      int off = br * 512 + lanew * 8;
      *reinterpret_cast<short8_t*>(AS + off)        = *reinterpret_cast<const short8_t*>(hi);
      *reinterpret_cast<short8_t*>(AS + 4096 + off) = *reinterpret_cast<const short8_t*>(lo);
    }
#pragma unroll
    for (int q = 0; q < 4; ++q) {
      int p = q >> 1, pass = q & 1;
      *reinterpret_cast<short8_t*>(BS + p * 4096 + (pass*256 + tid) * 8) = bvreg[q];
    }
    __syncthreads();

    // ---- issue next tile's global loads early (latency hides under MFMA)
    if (i + 1 < 192) {
      int ktg = ktBase + i + 1;
      int tap = ktg >> 7;
      int f0 = (ktg & 127) << 5;
#pragma unroll
      for (int u = 0; u < 2; ++u) {
        int row = u * 64 + rquot;
        int gm = m0 + row;
        int tt = (gm & 31) + tap - 1;
        if ((unsigned)tt < 32u) {
          const float* src = x + (size_t)(gm + tap - 1) * FIN + f0 + kb * 8;
          avreg[u*2+0] = *reinterpret_cast<const float4*>(src);
          avreg[u*2+1] = *reinterpret_cast<const float4*>(src + 4);
        } else {
          avreg[u*2+0] = make_float4(0,0,0,0);
          avreg[u*2+1] = make_float4(0,0,0,0);
        }
      }
      const unsigned short* bsrc = WT + ((size_t)ktg * 16 + by * 8) * 512;
#pragma unroll
      for (int q = 0; q < 4; ++q) {
        int p = q >> 1, pass = q & 1;
        bvreg[q] = *reinterpret_cast<const short8_t*>(bsrc + (size_t)p * PLANE + (pass*256 + tid) * 8);
      }
    }

    // ---- fragment reads + 48 MFMA (16 frag-pairs x3)
    short8_t bh[4], bl[4];
#pragma unroll
    for (int c = 0; c < 4; ++c) {
      int bc = wc * 4 + c;
      bh[c] = *reinterpret_cast<const short8_t*>(BS + bc * 512 + lane * 8);
      bl[c] = *reinterpret_cast<const short8_t*>(BS + 4096 + bc * 512 + lane * 8);
    }
#pragma unroll
    for (int r = 0; r < 4; ++r) {
      int br = wr * 4 + r;
      short8_t ah = *reinterpret_cast<const short8_t*>(AS + br * 512 + lane * 8);
      short8_t al = *reinterpret_cast<const short8_t*>(AS + 4096 + br * 512 + lane * 8);
#pragma unroll
      for (int c = 0; c < 4; ++c) {
        acc[r][c] = __builtin_amdgcn_mfma_f32_16x16x32_bf16(ah, bh[c], acc[r][c], 0, 0, 0);
        acc[r][c] = __builtin_amdgcn_mfma_f32_16x16x32_bf16(ah, bl[c], acc[r][c], 0, 0, 0);
        acc[r][c] = __builtin_amdgcn_mfma_f32_16x16x32_bf16(al, bh[c], acc[r][c], 0, 0, 0);
      }
    }
    __syncthreads();
  }

  // ---- epilogue: store partials
  float* P = PART + (size_t)blockIdx.z * ((size_t)NM * NL);
#pragma unroll
  for (int r = 0; r < 4; ++r) {
#pragma unroll
    for (int c = 0; c < 4; ++c) {
#pragma unroll
      for (int e = 0; e < 4; ++e) {
        int row = m0 + wr * 64 + r * 16 + ((lane >> 4) << 2) + e;
        int col = by * 128 + wc * 64 + c * 16 + (lane & 15);
        P[(size_t)row * NL + col] = acc[r][c][e];
      }
    }
  }
}

// ---------------- reduce split-K partials + bias -> feature
__global__ void __launch_bounds__(256) reduce_bias_k(const float* __restrict__ PART,
    const float* __restrict__ bias, float* __restrict__ feat) {
  int i = blockIdx.x * 256 + threadIdx.x;   // over NM*NL/4
  size_t base = (size_t)i * 4;
  float4 a = *reinterpret_cast<const float4*>(PART + base);
  float4 b = *reinterpret_cast<const float4*>(PART + (size_t)NM * NL + base);
  int c0 = (int)(base & 255);
  float4 bb = *reinterpret_cast<const float4*>(bias + c0);
  float4 o;
  o.x = a.x + b.x + bb.x;
  o.y = a.y + b.y + bb.y;
  o.z = a.z + b.z + bb.z;
  o.w = a.w + b.w + bb.w;
  *reinterpret_cast<float4*>(feat + base) = o;
}

// ---------------- generic C[M x N] = act(A[M x lda] @ W[N x ldw]^T + bias), ldc = N
template <int ACT>
__global__ void __launch_bounds__(256) gemm_wt_k(const float* __restrict__ A, int lda,
    const float* __restrict__ W, int ldw, int KB,
    const float* __restrict__ bias, float* __restrict__ C,
    int N, int K) {
  __shared__ float As[BK][LDT];
  __shared__ float Bs[BK][LDT];
  const int tid = threadIdx.x;
  const int m0 = blockIdx.x * BM;
  const int n0 = blockIdx.y * BN;
  const int row0 = (tid >> 4) << 3;
  const int col0 = (tid & 15) << 3;
  float acc[8][8] = {};
  for (int kk0 = 0; kk0 < K; kk0 += BK) {
#pragma unroll
    for (int i = 0; i < 4; ++i) {
      int v = i * 256 + tid;
      int row = v >> 3;
      int f4 = (v & 7) << 2;
      float4 val = *reinterpret_cast<const float4*>(A + (size_t)(m0 + row) * lda + kk0 + f4);
      As[f4 + 0][row] = val.x;
      As[f4 + 1][row] = val.y;
      As[f4 + 2][row] = val.z;
      As[f4 + 3][row] = val.w;
    }
#pragma unroll
    for (int i = 0; i < 4; ++i) {
      int v = i * 256 + tid;
      int n = v >> 3;
      int kq = (v & 7) << 2;
      int gn = n0 + n;
#pragma unroll
      for (int j = 0; j < 4; ++j) {
        int kk = kk0 + kq + j;
        float bv = 0.f;
        if (gn < N && kk < KB) bv = W[(size_t)gn * ldw + kk];
        Bs[kq + j][n] = bv;
      }
    }
    __syncthreads();
#pragma unroll
    for (int kk = 0; kk < BK; ++kk) {
      float a[8], b[8];
      *reinterpret_cast<float4*>(&a[0]) = *reinterpret_cast<const float4*>(&As[kk][row0]);
      *reinterpret_cast<float4*>(&a[4]) = *reinterpret_cast<const float4*>(&As[kk][row0 + 4]);
      *reinterpret_cast<float4*>(&b[0]) = *reinterpret_cast<const float4*>(&Bs[kk][col0]);
      *reinterpret_cast<float4*>(&b[4]) = *reinterpret_cast<const float4*>(&Bs[kk][col0 + 4]);
#pragma unroll
      for (int r = 0; r < 8; ++r)
#pragma unroll
        for (int c = 0; c < 8; ++c)
          acc[r][c] = fmaf(a[r], b[c], acc[r][c]);
    }
    __syncthreads();
  }
#pragma unroll
  for (int r = 0; r < 8; ++r) {
    int m = m0 + row0 + r;
#pragma unroll
    for (int c = 0; c < 8; ++c) {
      int n = n0 + col0 + c;
      if (n < N) {
        float v = acc[r][c] + bias[n];
        if (ACT == 1) v = fmaxf(v, 0.f);
        C[(size_t)m * (size_t)N + n] = v;
      }
    }
  }
}

// ---------------- gate: A[m] = gate_b + sum_d tanh(Yv)*sigmoid(Yu)*gw[d]
__global__ void __launch_bounds__(256) gate_k(const float* __restrict__ Yv,
    const float* __restrict__ Yu, const float* __restrict__ gw,
    const float* __restrict__ gb, float* __restrict__ Aws, float* __restrict__ At) {
  int lane = threadIdx.x & 63;
  int m = blockIdx.x * 4 + (threadIdx.x >> 6);
  float4 v4 = *reinterpret_cast<const float4*>(Yv + (size_t)m * ND + lane * 4);
  float4 u4 = *reinterpret_cast<const float4*>(Yu + (size_t)m * ND + lane * 4);
  float4 g4 = *reinterpret_cast<const float4*>(gw + lane * 4);
  float s = tanhf(v4.x) * sigmoidf_(u4.x) * g4.x
          + tanhf(v4.y) * sigmoidf_(u4.y) * g4.y
          + tanhf(v4.z) * sigmoidf_(u4.z) * g4.z
          + tanhf(v4.w) * sigmoidf_(u4.w) * g4.w;
#pragma unroll
  for (int off = 32; off > 0; off >>= 1) s += __shfl_xor(s, off, 64);
  if (lane == 0) {
    float a = s + gb[0];
    Aws[m] = a;
    At[m] = a;
  }
}

// ---------------- softmax over T then bag[b][l] = sum_t p_t feature[b][t][l]
__global__ void __launch_bounds__(256) softmax_bag_k(const float* __restrict__ Aws,
    const float* __restrict__ feat, float* __restrict__ bag) {
  __shared__ float av[NT];
  __shared__ float ev[NT];
  int b = blockIdx.x, tid = threadIdx.x;
  if (tid < NT) av[tid] = Aws[b * NT + tid];
  __syncthreads();
  float mx = -FLT_MAX;
#pragma unroll
  for (int t = 0; t < NT; ++t) mx = fmaxf(mx, av[t]);
  if (tid < NT) ev[tid] = expf(av[tid] - mx);
  __syncthreads();
  float ssum = 0.f;
#pragma unroll
  for (int t = 0; t < NT; ++t) ssum += ev[t];
  float accv = 0.f;
#pragma unroll
  for (int t = 0; t < NT; ++t) accv += ev[t] * feat[((size_t)b * NT + t) * NL + tid];
  bag[(size_t)b * NL + tid] = accv / ssum;
}

// ---------------- final 32->1 layer + sigmoid (+scale), strided output
__global__ void __launch_bounds__(256) rowdot32_k(const float* __restrict__ H,
    const float* __restrict__ w, const float* __restrict__ bptr,
    float* __restrict__ outp, int ostride, float scale) {
  int m = blockIdx.x * 256 + threadIdx.x;
  const float* h = H + (size_t)m * 32;
  float s = bptr[0];
#pragma unroll
  for (int i = 0; i < 32; i += 4) {
    float4 hv = *reinterpret_cast<const float4*>(h + i);
    float4 wv = *reinterpret_cast<const float4*>(w + i);
    s += hv.x * wv.x + hv.y * wv.y + hv.z * wv.z + hv.w * wv.w;
  }
  outp[(size_t)m * ostride] = scale * sigmoidf_(s);
}

// ---------------- seg_in = [feature | A | zero-pad] with row stride 288
__global__ void __launch_bounds__(64) make_segin_k(const float* __restrict__ feat,
    const float* __restrict__ Aws, float* __restrict__ segin) {
  int m = blockIdx.x, lane = threadIdx.x;
  float4 v = *reinterpret_cast<const float4*>(feat + (size_t)m * NL + lane * 4);
  *reinterpret_cast<float4*>(segin + (size_t)m * SEGLD + lane * 4) = v;
  if (lane == 0) segin[(size_t)m * SEGLD + 256] = Aws[m];
  if (lane >= 1 && lane < 32) segin[(size_t)m * SEGLD + 256 + lane] = 0.f;
}

// ---------------- per-sample 2-means cosine (100 iters), one wave per sample.
__global__ void __launch_bounds__(64) kmeans_k(const float* __restrict__ feat,
    const float* __restrict__ seg, float* __restrict__ assigns_out,
    float* __restrict__ outpair) {
  __shared__ float fls[NT][260];
  int b = blockIdx.x, lane = threadIdx.x;
  int l0 = lane << 2;
  float fn[NT][4];
#pragma unroll
  for (int t = 0; t < NT; ++t) {
    float4 v = *reinterpret_cast<const float4*>(feat + ((size_t)b * NT + t) * NL + l0);
    *reinterpret_cast<float4*>(&fls[t][l0]) = v;
    float ss = v.x * v.x + v.y * v.y + v.z * v.z + v.w * v.w;
#pragma unroll
    for (int off = 32; off > 0; off >>= 1) ss += __shfl_xor(ss, off, 64);
    float nr = sqrtf(ss) + 1e-8f;
    fn[t][0] = v.x / nr; fn[t][1] = v.y / nr; fn[t][2] = v.z / nr; fn[t][3] = v.w / nr;
  }
  __syncthreads();
  float cr0[4], cr1[4];
#pragma unroll
  for (int i = 0; i < 4; ++i) { cr0[i] = fls[0][l0 + i]; cr1[i] = fls[16][l0 + i]; }

  unsigned long long amask = 0ull;
  int c1n = 0;
  for (int it = 0; it < 100; ++it) {
    float ss0 = cr0[0]*cr0[0] + cr0[1]*cr0[1] + cr0[2]*cr0[2] + cr0[3]*cr0[3];
    float ss1 = cr1[0]*cr1[0] + cr1[1]*cr1[1] + cr1[2]*cr1[2] + cr1[3]*cr1[3];
#pragma unroll
    for (int off = 32; off > 0; off >>= 1) {
      ss0 += __shfl_xor(ss0, off, 64);
      ss1 += __shfl_xor(ss1, off, 64);
    }
    float nr0 = sqrtf(ss0) + 1e-8f, nr1 = sqrtf(ss1) + 1e-8f;
    float cn0[4], cn1[4];
#pragma unroll
    for (int i = 0; i < 4; ++i) { cn0[i] = cr0[i] / nr0; cn1[i] = cr1[i] / nr1; }
    float p[64];
#pragma unroll
    for (int t = 0; t < NT; ++t) {
      p[2*t]   = fn[t][0]*cn0[0] + fn[t][1]*cn0[1] + fn[t][2]*cn0[2] + fn[t][3]*cn0[3];
      p[2*t+1] = fn[t][0]*cn1[0] + fn[t][1]*cn1[1] + fn[t][2]*cn1[2] + fn[t][3]*cn1[3];
    }
    float v32[32];
    { bool hi = (lane & 32) != 0;
#pragma unroll
      for (int i = 0; i < 32; ++i) {
        float keep = hi ? p[32+i] : p[i];
        float send = hi ? p[i] : p[32+i];
        v32[i] = keep + __shfl_xor(send, 32, 64);
      } }
    float v16[16];
    { bool hi = (lane & 16) != 0;
#pragma unroll
      for (int i = 0; i < 16; ++i) {
        float keep = hi ? v32[16+i] : v32[i];
        float send = hi ? v32[i] : v32[16+i];
        v16[i] = keep + __shfl_xor(send, 16, 64);
      } }
    float v8[8];
    { bool hi = (lane & 8) != 0;
#pragma unroll
      for (int i = 0; i < 8; ++i) {
        float keep = hi ? v16[8+i] : v16[i];
        float send = hi ? v16[i] : v16[8+i];
        v8[i] = keep + __shfl_xor(send, 8, 64);
      } }
    float v4[4];
    { bool hi = (lane & 4) != 0;
#pragma unroll
      for (int i = 0; i < 4; ++i) {
        float keep = hi ? v8[4+i] : v8[i];
        float send = hi ? v8[i] : v8[4+i];
        v4[i] = keep + __shfl_xor(send, 4, 64);
      } }
    float v2[2];
    { bool hi = (lane & 2) != 0;
#pragma unroll
      for (int i = 0; i < 2; ++i) {
        float keep = hi ? v4[2+i] : v4[i];
        float send = hi ? v4[i] : v4[2+i];
        v2[i] = keep + __shfl_xor(send, 2, 64);
      } }
    float sim;
    { bool hi = (lane & 1) != 0;
      float keep = hi ? v2[1] : v2[0];
      float send = hi ? v2[0] : v2[1];
      sim = keep + __shfl_xor(send, 1, 64);
    }
    float simo = __shfl_xor(sim, 1, 64);
    bool is0 = (lane & 1) == 0;
    unsigned long long mask = __ballot(is0 && (simo > sim));
    int c1 = __popcll(mask);
    int c0 = NT - c1;
    float s0v[4] = {0,0,0,0}, s1v[4] = {0,0,0,0};
#pragma unroll
    for (int t = 0; t < NT; ++t) {
      float4 fv = *reinterpret_cast<const float4*>(&fls[t][l0]);
      if (mask & (1ull << (2*t))) {
        s1v[0] += fv.x; s1v[1] += fv.y; s1v[2] += fv.z; s1v[3] += fv.w;
      } else {
        s0v[0] += fv.x; s0v[1] += fv.y; s0v[2] += fv.z; s0v[3] += fv.w;
      }
    }
    float fc0 = fmaxf((float)c0, 1.0f), fc1 = fmaxf((float)c1, 1.0f);
#pragma unroll
    for (int i = 0; i < 4; ++i) {
      float n0v = s0v[i] / fc0;
      float n1v = s1v[i] / fc1;
      cr0[i] = (c0 > 0) ? n0v : cr0[i];
      cr1[i] = (c1 > 0) ? n1v : cr1[i];
    }
    amask = mask; c1n = c1;
  }
  if (lane < NT)
    assigns_out[(size_t)b * NT + lane] = (amask & (1ull << (2*lane))) ? 1.0f : 0.0f;
  if (lane == 0) {
    float sum0 = 0.f, sum1 = 0.f;
    for (int t = 0; t < NT; ++t) {
      float sv = seg[(size_t)b * NT + t];
      if (amask & (1ull << (2*t))) sum1 += sv; else sum0 += sv;
    }
    int c1 = c1n, c0 = NT - c1n;
    float m0 = (c0 > 0) ? (sum0 / fmaxf((float)c0, 1.f)) : -INFINITY;
    float m1 = (c1 > 0) ? (sum1 / fmaxf((float)c1, 1.f)) : -INFINITY;
    outpair[(size_t)b * 2 + 1] = 0.5f * fmaxf(m0, m1);
  }
}

extern "C" void kernel_launch(void* const* d_in, const int* in_sizes, int n_in,
                              void* d_out, int out_size, void* d_ws, size_t ws_size,
                              hipStream_t stream) {
  const float* x      = (const float*)d_in[0];
  const float* tsn_w  = (const float*)d_in[1];
  const float* tsn_b  = (const float*)d_in[2];
  const float* aV_w   = (const float*)d_in[3];
  const float* aV_b   = (const float*)d_in[4];
  const float* aU_w   = (const float*)d_in[5];
  const float* aU_b   = (const float*)d_in[6];
  const float* gate_w = (const float*)d_in[7];
  const float* gate_b = (const float*)d_in[8];
  const float* cb_w0  = (const float*)d_in[9];
  const float* cb_b0  = (const float*)d_in[10];
  const float* cb_w1  = (const float*)d_in[11];
  const float* cb_b1  = (const float*)d_in[12];
  const float* cb_w2  = (const float*)d_in[13];
  const float* cb_b2  = (const float*)d_in[14];
  const float* cb_w3  = (const float*)d_in[15];
  const float* cb_b3  = (const float*)d_in[16];
  const float* cs_w0  = (const float*)d_in[17];
  const float* cs_b0  = (const float*)d_in[18];
  const float* cs_w1  = (const float*)d_in[19];
  const float* cs_b1  = (const float*)d_in[20];
  const float* cs_w2  = (const float*)d_in[21];
  const float* cs_b2  = (const float*)d_in[22];
  const float* cs_w3  = (const float*)d_in[23];
  const float* cs_b3  = (const float*)d_in[24];

  float* out = (float*)d_out;
  float* o_feat   = out;                 // 4,194,304
  float* o_assign = out + 4194304;       // 16,384
  float* o_seg    = out + 4210688;       // 16,384
  float* o_out    = out + 4227072;       // 1,024 (B x 2)
  float* o_At     = out + 4228096;       // 16,384

  char* ws = (char*)d_ws;
  // conv phase: WT (12.58 MB) + PART (33.55 MB) -> 46.1 MB peak
  unsigned short* WT = (unsigned short*)ws;                 // 12,582,912 B
  float* PART  = (float*)(ws + 12582912);                   // 2 x 16,777,216 B (ends 46,137,344)
  // later phases (all after reduce) overlap the conv regions:
  float* YV    = (float*)ws;                                // 16.8 MB
  float* YU    = (float*)(ws + 16777216);                   // 16.8 MB
  float* SEGIN = (float*)ws;                                // 18.9 MB
  float* SH0   = (float*)(ws + 18874368);                   // 16.8 MB (ends 35,651,584)
  float* SH1   = (float*)ws;                                // 8.4 MB
  float* SH2   = (float*)(ws + 8388608);                    // 2.1 MB
  float* AWS   = (float*)(ws + 46137344);                   // 64 KB
  float* BAG   = (float*)(ws + 46202880);                   // 512 KB
  float* BH0   = (float*)(ws + 46727168);                   // 512 KB
  float* BH1   = (float*)(ws + 47251456);                   // 256 KB
  float* BH2   = (float*)(ws + 47513600);                   // 64 KB (end 47,579,136)

  // 1) conv weight repack (fragment-linear hi/lo bf16)
  repack_frag_k<<<dim3(12288), dim3(256), 0, stream>>>(tsn_w, WT);
  // 2) conv as bf16x3 MFMA GEMM, split-K=2
  conv_mfma_k<<<dim3(128, 2, 2), dim3(256), 0, stream>>>(x, WT, PART);
  // 3) reduce partials + bias -> feature
  reduce_bias_k<<<dim3(4096), dim3(256), 0, stream>>>(PART, tsn_b, o_feat);
  // 4-5) attention projections
  gemm_wt_k<0><<<dim3(128, 2), dim3(256), 0, stream>>>(o_feat, 256, aV_w, 256, 256, aV_b, YV, 256, 256);
  gemm_wt_k<0><<<dim3(128, 2), dim3(256), 0, stream>>>(o_feat, 256, aU_w, 256, 256, aU_b, YU, 256, 256);
  // 6) gate -> A (ws) and At (out)
  gate_k<<<dim3(4096), dim3(256), 0, stream>>>(YV, YU, gate_w, gate_b, AWS, o_At);
  // 7) softmax over T + bag
  softmax_bag_k<<<dim3(512), dim3(256), 0, stream>>>(AWS, o_feat, BAG);
  // 8-11) bag classifier -> output[:,0]
  gemm_wt_k<1><<<dim3(4, 2), dim3(256), 0, stream>>>(BAG, 256, cb_w0, 256, 256, cb_b0, BH0, 256, 256);
  gemm_wt_k<1><<<dim3(4, 1), dim3(256), 0, stream>>>(BH0, 256, cb_w1, 256, 256, cb_b1, BH1, 128, 256);
  gemm_wt_k<1><<<dim3(4, 1), dim3(256), 0, stream>>>(BH1, 128, cb_w2, 128, 128, cb_b2, BH2, 32, 128);
  rowdot32_k<<<dim3(2), dim3(256), 0, stream>>>(BH2, cb_w3, cb_b3, o_out, 2, 0.5f);
  // 12) seg input concat
  make_segin_k<<<dim3(16384), dim3(64), 0, stream>>>(o_feat, AWS, SEGIN);
  // 13-16) seg classifier -> output_seg
  gemm_wt_k<1><<<dim3(128, 2), dim3(256), 0, stream>>>(SEGIN, SEGLD, cs_w0, 257, 257, cs_b0, SH0, 256, SEGLD);
  gemm_wt_k<1><<<dim3(128, 1), dim3(256), 0, stream>>>(SH0, 256, cs_w1, 256, 256, cs_b1, SH1, 128, 256);
  gemm_wt_k<1><<<dim3(128, 1), dim3(256), 0, stream>>>(SH1, 128, cs_w2, 128, 128, cs_b2, SH2, 32, 128);
  rowdot32_k<<<dim3(64), dim3(256), 0, stream>>>(SH2, cs_w3, cs_b3, o_seg, 1, 1.0f);
  // 17) kmeans -> assigns + output[:,1]
  kmeans_k<<<dim3(512), dim3(64), 0, stream>>>(o_feat, o_seg, o_assign, o_out);
}

// Round 3
// 625.643 us; speedup vs baseline: 4.9910x; 1.9716x over previous
//
#include <hip/hip_runtime.h>
#include <cfloat>
#include <cmath>

#define NB 512
#define NT 32
#define FIN 4096
#define NL 256
#define ND 256
#define NM (NB*NT)        // 16384
#define KCONV (3*FIN)     // 12288
#define PLANE 3145728     // ushorts per conv weight plane (12288*256)

#define BM 128
#define BN 128
#define BK 32
#define LDT 132           // padded LDS tile stride for fp32 path

typedef __attribute__((ext_vector_type(8))) short short8_t;
typedef __attribute__((ext_vector_type(4))) float f32x4;

__device__ __forceinline__ float sigmoidf_(float v) { return 1.0f / (1.0f + expf(-v)); }

__device__ __forceinline__ unsigned short f2bf(float v) {
  unsigned u = __float_as_uint(v);
  unsigned r = u + 0x7FFFu + ((u >> 16) & 1u);
  return (unsigned short)(r >> 16);
}
__device__ __forceinline__ float bf2f(unsigned short h) {
  return __uint_as_float(((unsigned)h) << 16);
}

// ---------------- repack conv weights into MFMA-fragment-linear hi/lo bf16 planes.
__global__ void __launch_bounds__(256) repack_frag_k(const float* __restrict__ w,
                                                     unsigned short* __restrict__ wt) {
  int d = blockIdx.x * 256 + threadIdx.x;   // over 3,145,728
  int kt = d >> 13;
  int bc = (d >> 9) & 15;
  int lane = (d >> 3) & 63;
  int j = d & 7;
  int kb = lane >> 4;
  int kk = kt * 32 + kb * 8 + j;
  int l = bc * 16 + (lane & 15);
  int tap = kk >> 12;
  int f = kk & 4095;
  float v = w[(size_t)l * KCONV + f * 3 + tap];
  unsigned short hi = f2bf(v);
  unsigned short lo = f2bf(v - bf2f(hi));
  wt[d] = hi;
  wt[PLANE + d] = lo;
}

// ---------------- generic dense-weight repack into fragment-linear hi/lo planes.
// layout: d = ((kt*N16 + bc)*64 + lane)*8 + j ; kk = kt*32 + (lane>>4)*8 + j ; l = bc*16+(lane&15)
// src: l < nsplit ? W1[l*ldw+kk] : W2[(l-nsplit)*ldw+kk]; kk >= KB -> 0
__global__ void __launch_bounds__(256) repack_dense_k(const float* __restrict__ W1,
    const float* __restrict__ W2, int nsplit, int ldw, int KB, int N16,
    unsigned short* __restrict__ wt, int planeElems) {
  int d = blockIdx.x * 256 + threadIdx.x;
  if (d >= planeElems) return;
  int j = d & 7;
  int lane = (d >> 3) & 63;
  int bckt = d >> 9;
  int bc = bckt % N16;
  int kt = bckt / N16;
  int kk = kt * 32 + (lane >> 4) * 8 + j;
  int l = bc * 16 + (lane & 15);
  float v = 0.f;
  if (kk < KB) {
    if (l < nsplit) v = W1[(size_t)l * ldw + kk];
    else            v = W2[(size_t)(l - nsplit) * ldw + kk];
  }
  unsigned short hi = f2bf(v);
  unsigned short lo = f2bf(v - bf2f(hi));
  wt[d] = hi;
  wt[planeElems + d] = lo;
}

// ---------------- conv as bf16x3 MFMA GEMM, split-K=2, 128x128 tile, 4 waves.
__global__ void __launch_bounds__(256) conv_mfma_k(const float* __restrict__ x,
    const unsigned short* __restrict__ WT, float* __restrict__ PART) {
  __shared__ __align__(16) unsigned short AS[8192];
  __shared__ __align__(16) unsigned short BS[8192];
  const int tid = threadIdx.x;
  const int m0 = blockIdx.x * 128;
  const int by = blockIdx.y;
  const int ktBase = blockIdx.z * 192;
  const int lane = tid & 63;
  const int w = tid >> 6, wr = w >> 1, wc = w & 1;
  const int kb = tid & 3;
  const int rquot = tid >> 2;

  f32x4 acc[4][4] = {};
  float4 avreg[4];
  short8_t bvreg[4];

  {
    int ktg = ktBase;
    int tap = ktg >> 7;
    int f0 = (ktg & 127) << 5;
#pragma unroll
    for (int u = 0; u < 2; ++u) {
      int row = u * 64 + rquot;
      int gm = m0 + row;
      int tt = (gm & 31) + tap - 1;
      if ((unsigned)tt < 32u) {
        const float* src = x + (size_t)(gm + tap - 1) * FIN + f0 + kb * 8;
        avreg[u*2+0] = *reinterpret_cast<const float4*>(src);
        avreg[u*2+1] = *reinterpret_cast<const float4*>(src + 4);
      } else {
        avreg[u*2+0] = make_float4(0,0,0,0);
        avreg[u*2+1] = make_float4(0,0,0,0);
      }
    }
    const unsigned short* bsrc = WT + ((size_t)ktg * 16 + by * 8) * 512;
#pragma unroll
    for (int q = 0; q < 4; ++q) {
      int p = q >> 1, pass = q & 1;
      bvreg[q] = *reinterpret_cast<const short8_t*>(bsrc + (size_t)p * PLANE + (pass*256 + tid) * 8);
    }
  }

  for (int i = 0; i < 192; ++i) {
#pragma unroll
    for (int u = 0; u < 2; ++u) {
      float vv[8];
      *reinterpret_cast<float4*>(&vv[0]) = avreg[u*2+0];
      *reinterpret_cast<float4*>(&vv[4]) = avreg[u*2+1];
      __align__(16) unsigned short hi[8];
      __align__(16) unsigned short lo[8];
#pragma unroll
      for (int e = 0; e < 8; ++e) {
        float v = vv[e];
        v = (v == v) ? v : 0.0f;
        unsigned short h = f2bf(v);
        hi[e] = h;
        lo[e] = f2bf(v - bf2f(h));
      }
      int row = u * 64 + rquot;
      int br = row >> 4;
      int lanew = (row & 15) + (kb << 4);
      int off = br * 512 + lanew * 8;
      *reinterpret_cast<short8_t*>(AS + off)        = *reinterpret_cast<const short8_t*>(hi);
      *reinterpret_cast<short8_t*>(AS + 4096 + off) = *reinterpret_cast<const short8_t*>(lo);
    }
#pragma unroll
    for (int q = 0; q < 4; ++q) {
      int p = q >> 1, pass = q & 1;
      *reinterpret_cast<short8_t*>(BS + p * 4096 + (pass*256 + tid) * 8) = bvreg[q];
    }
    __syncthreads();

    if (i + 1 < 192) {
      int ktg = ktBase + i + 1;
      int tap = ktg >> 7;
      int f0 = (ktg & 127) << 5;
#pragma unroll
      for (int u = 0; u < 2; ++u) {
        int row = u * 64 + rquot;
        int gm = m0 + row;
        int tt = (gm & 31) + tap - 1;
        if ((unsigned)tt < 32u) {
          const float* src = x + (size_t)(gm + tap - 1) * FIN + f0 + kb * 8;
          avreg[u*2+0] = *reinterpret_cast<const float4*>(src);
          avreg[u*2+1] = *reinterpret_cast<const float4*>(src + 4);
        } else {
          avreg[u*2+0] = make_float4(0,0,0,0);
          avreg[u*2+1] = make_float4(0,0,0,0);
        }
      }
      const unsigned short* bsrc = WT + ((size_t)ktg * 16 + by * 8) * 512;
#pragma unroll
      for (int q = 0; q < 4; ++q) {
        int p = q >> 1, pass = q & 1;
        bvreg[q] = *reinterpret_cast<const short8_t*>(bsrc + (size_t)p * PLANE + (pass*256 + tid) * 8);
      }
    }

    short8_t bh[4], bl[4];
#pragma unroll
    for (int c = 0; c < 4; ++c) {
      int bc = wc * 4 + c;
      bh[c] = *reinterpret_cast<const short8_t*>(BS + bc * 512 + lane * 8);
      bl[c] = *reinterpret_cast<const short8_t*>(BS + 4096 + bc * 512 + lane * 8);
    }
#pragma unroll
    for (int r = 0; r < 4; ++r) {
      int br = wr * 4 + r;
      short8_t ah = *reinterpret_cast<const short8_t*>(AS + br * 512 + lane * 8);
      short8_t al = *reinterpret_cast<const short8_t*>(AS + 4096 + br * 512 + lane * 8);
#pragma unroll
      for (int c = 0; c < 4; ++c) {
        acc[r][c] = __builtin_amdgcn_mfma_f32_16x16x32_bf16(ah, bh[c], acc[r][c], 0, 0, 0);
        acc[r][c] = __builtin_amdgcn_mfma_f32_16x16x32_bf16(ah, bl[c], acc[r][c], 0, 0, 0);
        acc[r][c] = __builtin_amdgcn_mfma_f32_16x16x32_bf16(al, bh[c], acc[r][c], 0, 0, 0);
      }
    }
    __syncthreads();
  }

  float* P = PART + (size_t)blockIdx.z * ((size_t)NM * NL);
#pragma unroll
  for (int r = 0; r < 4; ++r) {
#pragma unroll
    for (int c = 0; c < 4; ++c) {
#pragma unroll
      for (int e = 0; e < 4; ++e) {
        int row = m0 + wr * 64 + r * 16 + ((lane >> 4) << 2) + e;
        int col = by * 128 + wc * 64 + c * 16 + (lane & 15);
        P[(size_t)row * NL + col] = acc[r][c][e];
      }
    }
  }
}

// ---------------- reduce split-K partials + bias -> feature
__global__ void __launch_bounds__(256) reduce_bias_k(const float* __restrict__ PART,
    const float* __restrict__ bias, float* __restrict__ feat) {
  int i = blockIdx.x * 256 + threadIdx.x;
  size_t base = (size_t)i * 4;
  float4 a = *reinterpret_cast<const float4*>(PART + base);
  float4 b = *reinterpret_cast<const float4*>(PART + (size_t)NM * NL + base);
  int c0 = (int)(base & 255);
  float4 bb = *reinterpret_cast<const float4*>(bias + c0);
  float4 o;
  o.x = a.x + b.x + bb.x;
  o.y = a.y + b.y + bb.y;
  o.z = a.z + b.z + bb.z;
  o.w = a.w + b.w + bb.w;
  *reinterpret_cast<float4*>(feat + base) = o;
}

// ---------------- generic bf16x3 MFMA GEMM: C[M x N] = act(A_fp32 @ Wfrag + bias)
// SEG=1: A has K=257 logical cols: 0..255 from A (lda), col 256 = Aws[m], rest 0.
// bias: col < bsplit ? bias1[col] : bias2[col-bsplit]
template <int ACT, int SEG>
__global__ void __launch_bounds__(256) mfma_gemm_k(const float* __restrict__ A, int lda,
    const float* __restrict__ Aws, const unsigned short* __restrict__ WT,
    int planeElems, int N16, int KT,
    const float* __restrict__ bias1, const float* __restrict__ bias2, int bsplit,
    float* __restrict__ C, int N) {
  __shared__ __align__(16) unsigned short AS[8192];
  __shared__ __align__(16) unsigned short BS[8192];
  const int tid = threadIdx.x;
  const int m0 = blockIdx.x * 128;
  const int by = blockIdx.y;
  const int lane = tid & 63;
  const int w = tid >> 6, wr = w >> 1, wc = w & 1;
  const int kb = tid & 3;
  const int rquot = tid >> 2;

  f32x4 acc[4][4] = {};
  float4 avreg[4];
  short8_t bvreg[4];

  {
    int kk0 = 0;
#pragma unroll
    for (int u = 0; u < 2; ++u) {
      int gm = m0 + u * 64 + rquot;
      const float* src = A + (size_t)gm * lda + kk0 + kb * 8;
      avreg[u*2+0] = *reinterpret_cast<const float4*>(src);
      avreg[u*2+1] = *reinterpret_cast<const float4*>(src + 4);
    }
    const unsigned short* bsrc = WT + ((size_t)(0 * N16) + by * 8) * 512;
#pragma unroll
    for (int q = 0; q < 4; ++q) {
      int p = q >> 1, pass = q & 1;
      bvreg[q] = *reinterpret_cast<const short8_t*>(bsrc + (size_t)p * planeElems * 8 / 8
                  + (size_t)p * 0 + (pass*256 + tid) * 8 + (size_t)(p ? planeElems - planeElems : 0));
    }
    // (rewritten cleanly below in-loop; prologue uses same expression)
#pragma unroll
    for (int q = 0; q < 4; ++q) {
      int p = q >> 1, pass = q & 1;
      bvreg[q] = *reinterpret_cast<const short8_t*>(WT + (size_t)p * planeElems
                  + ((size_t)by * 8) * 512 + (pass*256 + tid) * 8);
    }
  }

  for (int i = 0; i < KT; ++i) {
#pragma unroll
    for (int u = 0; u < 2; ++u) {
      float vv[8];
      *reinterpret_cast<float4*>(&vv[0]) = avreg[u*2+0];
      *reinterpret_cast<float4*>(&vv[4]) = avreg[u*2+1];
      __align__(16) unsigned short hi[8];
      __align__(16) unsigned short lo[8];
#pragma unroll
      for (int e = 0; e < 8; ++e) {
        float v = vv[e];
        unsigned short h = f2bf(v);
        hi[e] = h;
        lo[e] = f2bf(v - bf2f(h));
      }
      int row = u * 64 + rquot;
      int br = row >> 4;
      int lanew = (row & 15) + (kb << 4);
      int off = br * 512 + lanew * 8;
      *reinterpret_cast<short8_t*>(AS + off)        = *reinterpret_cast<const short8_t*>(hi);
      *reinterpret_cast<short8_t*>(AS + 4096 + off) = *reinterpret_cast<const short8_t*>(lo);
    }
#pragma unroll
    for (int q = 0; q < 4; ++q) {
      int p = q >> 1, pass = q & 1;
      *reinterpret_cast<short8_t*>(BS + p * 4096 + (pass*256 + tid) * 8) = bvreg[q];
    }
    __syncthreads();

    if (i + 1 < KT) {
      int kk0 = (i + 1) * 32;
#pragma unroll
      for (int u = 0; u < 2; ++u) {
        int gm = m0 + u * 64 + rquot;
        if (SEG && kk0 >= 256) {
          float a0 = (kb == 0) ? Aws[gm] : 0.f;
          avreg[u*2+0] = make_float4(a0, 0.f, 0.f, 0.f);
          avreg[u*2+1] = make_float4(0.f, 0.f, 0.f, 0.f);
        } else {
          const float* src = A + (size_t)gm * lda + kk0 + kb * 8;
          avreg[u*2+0] = *reinterpret_cast<const float4*>(src);
          avreg[u*2+1] = *reinterpret_cast<const float4*>(src + 4);
        }
      }
#pragma unroll
      for (int q = 0; q < 4; ++q) {
        int p = q >> 1, pass = q & 1;
        bvreg[q] = *reinterpret_cast<const short8_t*>(WT + (size_t)p * planeElems
                    + ((size_t)(i + 1) * N16 + by * 8) * 512 + (pass*256 + tid) * 8);
      }
    }

    short8_t bh[4], bl[4];
#pragma unroll
    for (int c = 0; c < 4; ++c) {
      int bc = wc * 4 + c;
      bh[c] = *reinterpret_cast<const short8_t*>(BS + bc * 512 + lane * 8);
      bl[c] = *reinterpret_cast<const short8_t*>(BS + 4096 + bc * 512 + lane * 8);
    }
#pragma unroll
    for (int r = 0; r < 4; ++r) {
      int br = wr * 4 + r;
      short8_t ah = *reinterpret_cast<const short8_t*>(AS + br * 512 + lane * 8);
      short8_t al = *reinterpret_cast<const short8_t*>(AS + 4096 + br * 512 + lane * 8);
#pragma unroll
      for (int c = 0; c < 4; ++c) {
        acc[r][c] = __builtin_amdgcn_mfma_f32_16x16x32_bf16(ah, bh[c], acc[r][c], 0, 0, 0);
        acc[r][c] = __builtin_amdgcn_mfma_f32_16x16x32_bf16(ah, bl[c], acc[r][c], 0, 0, 0);
        acc[r][c] = __builtin_amdgcn_mfma_f32_16x16x32_bf16(al, bh[c], acc[r][c], 0, 0, 0);
      }
    }
    __syncthreads();
  }

#pragma unroll
  for (int r = 0; r < 4; ++r) {
#pragma unroll
    for (int c = 0; c < 4; ++c) {
#pragma unroll
      for (int e = 0; e < 4; ++e) {
        int row = m0 + wr * 64 + r * 16 + ((lane >> 4) << 2) + e;
        int col = by * 128 + wc * 64 + c * 16 + (lane & 15);
        float b = (col < bsplit) ? bias1[col] : bias2[col - bsplit];
        float v = acc[r][c][e] + b;
        if (ACT == 1) v = fmaxf(v, 0.f);
        C[(size_t)row * N + col] = v;
      }
    }
  }
}

// ---------------- fp32 fallback GEMM (small layers)
template <int ACT>
__global__ void __launch_bounds__(256) gemm_wt_k(const float* __restrict__ A, int lda,
    const float* __restrict__ W, int ldw, int KB,
    const float* __restrict__ bias, float* __restrict__ C,
    int N, int K) {
  __shared__ float As[BK][LDT];
  __shared__ float Bs[BK][LDT];
  const int tid = threadIdx.x;
  const int m0 = blockIdx.x * BM;
  const int n0 = blockIdx.y * BN;
  const int row0 = (tid >> 4) << 3;
  const int col0 = (tid & 15) << 3;
  float acc[8][8] = {};
  for (int kk0 = 0; kk0 < K; kk0 += BK) {
#pragma unroll
    for (int i = 0; i < 4; ++i) {
      int v = i * 256 + tid;
      int row = v >> 3;
      int f4 = (v & 7) << 2;
      float4 val = *reinterpret_cast<const float4*>(A + (size_t)(m0 + row) * lda + kk0 + f4);
      As[f4 + 0][row] = val.x;
      As[f4 + 1][row] = val.y;
      As[f4 + 2][row] = val.z;
      As[f4 + 3][row] = val.w;
    }
#pragma unroll
    for (int i = 0; i < 4; ++i) {
      int v = i * 256 + tid;
      int n = v >> 3;
      int kq = (v & 7) << 2;
      int gn = n0 + n;
#pragma unroll
      for (int j = 0; j < 4; ++j) {
        int kk = kk0 + kq + j;
        float bv = 0.f;
        if (gn < N && kk < KB) bv = W[(size_t)gn * ldw + kk];
        Bs[kq + j][n] = bv;
      }
    }
    __syncthreads();
#pragma unroll
    for (int kk = 0; kk < BK; ++kk) {
      float a[8], b[8];
      *reinterpret_cast<float4*>(&a[0]) = *reinterpret_cast<const float4*>(&As[kk][row0]);
      *reinterpret_cast<float4*>(&a[4]) = *reinterpret_cast<const float4*>(&As[kk][row0 + 4]);
      *reinterpret_cast<float4*>(&b[0]) = *reinterpret_cast<const float4*>(&Bs[kk][col0]);
      *reinterpret_cast<float4*>(&b[4]) = *reinterpret_cast<const float4*>(&Bs[kk][col0 + 4]);
#pragma unroll
      for (int r = 0; r < 8; ++r)
#pragma unroll
        for (int c = 0; c < 8; ++c)
          acc[r][c] = fmaf(a[r], b[c], acc[r][c]);
    }
    __syncthreads();
  }
#pragma unroll
  for (int r = 0; r < 8; ++r) {
    int m = m0 + row0 + r;
#pragma unroll
    for (int c = 0; c < 8; ++c) {
      int n = n0 + col0 + c;
      if (n < N) {
        float v = acc[r][c] + bias[n];
        if (ACT == 1) v = fmaxf(v, 0.f);
        C[(size_t)m * (size_t)N + n] = v;
      }
    }
  }
}

// ---------------- gate from fused Y=[YV|YU] (row stride 512)
__global__ void __launch_bounds__(256) gate_k(const float* __restrict__ Y,
    const float* __restrict__ gw, const float* __restrict__ gb,
    float* __restrict__ Aws, float* __restrict__ At) {
  int lane = threadIdx.x & 63;
  int m = blockIdx.x * 4 + (threadIdx.x >> 6);
  float4 v4 = *reinterpret_cast<const float4*>(Y + (size_t)m * 512 + lane * 4);
  float4 u4 = *reinterpret_cast<const float4*>(Y + (size_t)m * 512 + 256 + lane * 4);
  float4 g4 = *reinterpret_cast<const float4*>(gw + lane * 4);
  float s = tanhf(v4.x) * sigmoidf_(u4.x) * g4.x
          + tanhf(v4.y) * sigmoidf_(u4.y) * g4.y
          + tanhf(v4.z) * sigmoidf_(u4.z) * g4.z
          + tanhf(v4.w) * sigmoidf_(u4.w) * g4.w;
#pragma unroll
  for (int off = 32; off > 0; off >>= 1) s += __shfl_xor(s, off, 64);
  if (lane == 0) {
    float a = s + gb[0];
    Aws[m] = a;
    At[m] = a;
  }
}

// ---------------- softmax over T then bag
__global__ void __launch_bounds__(256) softmax_bag_k(const float* __restrict__ Aws,
    const float* __restrict__ feat, float* __restrict__ bag) {
  __shared__ float av[NT];
  __shared__ float ev[NT];
  int b = blockIdx.x, tid = threadIdx.x;
  if (tid < NT) av[tid] = Aws[b * NT + tid];
  __syncthreads();
  float mx = -FLT_MAX;
#pragma unroll
  for (int t = 0; t < NT; ++t) mx = fmaxf(mx, av[t]);
  if (tid < NT) ev[tid] = expf(av[tid] - mx);
  __syncthreads();
  float ssum = 0.f;
#pragma unroll
  for (int t = 0; t < NT; ++t) ssum += ev[t];
  float accv = 0.f;
#pragma unroll
  for (int t = 0; t < NT; ++t) accv += ev[t] * feat[((size_t)b * NT + t) * NL + tid];
  bag[(size_t)b * NL + tid] = accv / ssum;
}

// ---------------- final 32->1 layer + sigmoid, strided output
__global__ void __launch_bounds__(256) rowdot32_k(const float* __restrict__ H,
    const float* __restrict__ w, const float* __restrict__ bptr,
    float* __restrict__ outp, int ostride, float scale) {
  int m = blockIdx.x * 256 + threadIdx.x;
  const float* h = H + (size_t)m * 32;
  float s = bptr[0];
#pragma unroll
  for (int i = 0; i < 32; i += 4) {
    float4 hv = *reinterpret_cast<const float4*>(h + i);
    float4 wv = *reinterpret_cast<const float4*>(w + i);
    s += hv.x * wv.x + hv.y * wv.y + hv.z * wv.z + hv.w * wv.w;
  }
  outp[(size_t)m * ostride] = scale * sigmoidf_(s);
}

// ---------------- per-sample 2-means cosine, one wave per sample, early fixed-point break.
__global__ void __launch_bounds__(64) kmeans_k(const float* __restrict__ feat,
    const float* __restrict__ seg, float* __restrict__ assigns_out,
    float* __restrict__ outpair) {
  __shared__ float fls[NT][260];
  int b = blockIdx.x, lane = threadIdx.x;
  int l0 = lane << 2;
  float fn[NT][4];
#pragma unroll
  for (int t = 0; t < NT; ++t) {
    float4 v = *reinterpret_cast<const float4*>(feat + ((size_t)b * NT + t) * NL + l0);
    *reinterpret_cast<float4*>(&fls[t][l0]) = v;
    float ss = v.x * v.x + v.y * v.y + v.z * v.z + v.w * v.w;
#pragma unroll
    for (int off = 32; off > 0; off >>= 1) ss += __shfl_xor(ss, off, 64);
    float nr = sqrtf(ss) + 1e-8f;
    fn[t][0] = v.x / nr; fn[t][1] = v.y / nr; fn[t][2] = v.z / nr; fn[t][3] = v.w / nr;
  }
  __syncthreads();
  float cr0[4], cr1[4];
#pragma unroll
  for (int i = 0; i < 4; ++i) { cr0[i] = fls[0][l0 + i]; cr1[i] = fls[16][l0 + i]; }

  unsigned long long amask = 0ull;
  unsigned long long prev = ~0ull;   // impossible value (mask uses only even bit positions)
  int c1n = 0;
  for (int it = 0; it < 100; ++it) {
    float ss0 = cr0[0]*cr0[0] + cr0[1]*cr0[1] + cr0[2]*cr0[2] + cr0[3]*cr0[3];
    float ss1 = cr1[0]*cr1[0] + cr1[1]*cr1[1] + cr1[2]*cr1[2] + cr1[3]*cr1[3];
#pragma unroll
    for (int off = 32; off > 0; off >>= 1) {
      ss0 += __shfl_xor(ss0, off, 64);
      ss1 += __shfl_xor(ss1, off, 64);
    }
    float nr0 = sqrtf(ss0) + 1e-8f, nr1 = sqrtf(ss1) + 1e-8f;
    float cn0[4], cn1[4];
#pragma unroll
    for (int i = 0; i < 4; ++i) { cn0[i] = cr0[i] / nr0; cn1[i] = cr1[i] / nr1; }
    float p[64];
#pragma unroll
    for (int t = 0; t < NT; ++t) {
      p[2*t]   = fn[t][0]*cn0[0] + fn[t][1]*cn0[1] + fn[t][2]*cn0[2] + fn[t][3]*cn0[3];
      p[2*t+1] = fn[t][0]*cn1[0] + fn[t][1]*cn1[1] + fn[t][2]*cn1[2] + fn[t][3]*cn1[3];
    }
    float v32[32];
    { bool hi = (lane & 32) != 0;
#pragma unroll
      for (int i = 0; i < 32; ++i) {
        float keep = hi ? p[32+i] : p[i];
        float send = hi ? p[i] : p[32+i];
        v32[i] = keep + __shfl_xor(send, 32, 64);
      } }
    float v16[16];
    { bool hi = (lane & 16) != 0;
#pragma unroll
      for (int i = 0; i < 16; ++i) {
        float keep = hi ? v32[16+i] : v32[i];
        float send = hi ? v32[i] : v32[16+i];
        v16[i] = keep + __shfl_xor(send, 16, 64);
      } }
    float v8[8];
    { bool hi = (lane & 8) != 0;
#pragma unroll
      for (int i = 0; i < 8; ++i) {
        float keep = hi ? v16[8+i] : v16[i];
        float send = hi ? v16[i] : v16[8+i];
        v8[i] = keep + __shfl_xor(send, 8, 64);
      } }
    float v4[4];
    { bool hi = (lane & 4) != 0;
#pragma unroll
      for (int i = 0; i < 4; ++i) {
        float keep = hi ? v8[4+i] : v8[i];
        float send = hi ? v8[i] : v8[4+i];
        v4[i] = keep + __shfl_xor(send, 4, 64);
      } }
    float v2[2];
    { bool hi = (lane & 2) != 0;
#pragma unroll
      for (int i = 0; i < 2; ++i) {
        float keep = hi ? v4[2+i] : v4[i];
        float send = hi ? v4[i] : v4[2+i];
        v2[i] = keep + __shfl_xor(send, 2, 64);
      } }
    float sim;
    { bool hi = (lane & 1) != 0;
      float keep = hi ? v2[1] : v2[0];
      float send = hi ? v2[0] : v2[1];
      sim = keep + __shfl_xor(send, 1, 64);
    }
    float simo = __shfl_xor(sim, 1, 64);
    bool is0 = (lane & 1) == 0;
    unsigned long long mask = __ballot(is0 && (simo > sim));
    int c1 = __popcll(mask);
    int c0 = NT - c1;
    amask = mask; c1n = c1;
    if (mask == prev) break;     // fixed point: all remaining iterations reproduce this mask
    prev = mask;
    // per-cluster sums via mask-FMA (adding exact 0.0 preserves sequential order bitwise)
    float s0v[4] = {0,0,0,0}, s1v[4] = {0,0,0,0};
#pragma unroll
    for (int t = 0; t < NT; ++t) {
      float mt = (float)((mask >> (2*t)) & 1ull);
      float nt = 1.0f - mt;
      float4 fv = *reinterpret_cast<const float4*>(&fls[t][l0]);
      s1v[0] = fmaf(mt, fv.x, s1v[0]); s1v[1] = fmaf(mt, fv.y, s1v[1]);
      s1v[2] = fmaf(mt, fv.z, s1v[2]); s1v[3] = fmaf(mt, fv.w, s1v[3]);
      s0v[0] = fmaf(nt, fv.x, s0v[0]); s0v[1] = fmaf(nt, fv.y, s0v[1]);
      s0v[2] = fmaf(nt, fv.z, s0v[2]); s0v[3] = fmaf(nt, fv.w, s0v[3]);
    }
    float fc0 = fmaxf((float)c0, 1.0f), fc1 = fmaxf((float)c1, 1.0f);
#pragma unroll
    for (int i = 0; i < 4; ++i) {
      float n0v = s0v[i] / fc0;
      float n1v = s1v[i] / fc1;
      cr0[i] = (c0 > 0) ? n0v : cr0[i];
      cr1[i] = (c1 > 0) ? n1v : cr1[i];
    }
  }
  if (lane < NT)
    assigns_out[(size_t)b * NT + lane] = (amask & (1ull << (2*lane))) ? 1.0f : 0.0f;
  if (lane == 0) {
    float sum0 = 0.f, sum1 = 0.f;
    for (int t = 0; t < NT; ++t) {
      float sv = seg[(size_t)b * NT + t];
      if (amask & (1ull << (2*t))) sum1 += sv; else sum0 += sv;
    }
    int c1 = c1n, c0 = NT - c1n;
    float m0 = (c0 > 0) ? (sum0 / fmaxf((float)c0, 1.f)) : -INFINITY;
    float m1 = (c1 > 0) ? (sum1 / fmaxf((float)c1, 1.f)) : -INFINITY;
    outpair[(size_t)b * 2 + 1] = 0.5f * fmaxf(m0, m1);
  }
}

extern "C" void kernel_launch(void* const* d_in, const int* in_sizes, int n_in,
                              void* d_out, int out_size, void* d_ws, size_t ws_size,
                              hipStream_t stream) {
  const float* x      = (const float*)d_in[0];
  const float* tsn_w  = (const float*)d_in[1];
  const float* tsn_b  = (const float*)d_in[2];
  const float* aV_w   = (const float*)d_in[3];
  const float* aV_b   = (const float*)d_in[4];
  const float* aU_w   = (const float*)d_in[5];
  const float* aU_b   = (const float*)d_in[6];
  const float* gate_w = (const float*)d_in[7];
  const float* gate_b = (const float*)d_in[8];
  const float* cb_w0  = (const float*)d_in[9];
  const float* cb_b0  = (const float*)d_in[10];
  const float* cb_w1  = (const float*)d_in[11];
  const float* cb_b1  = (const float*)d_in[12];
  const float* cb_w2  = (const float*)d_in[13];
  const float* cb_b2  = (const float*)d_in[14];
  const float* cb_w3  = (const float*)d_in[15];
  const float* cb_b3  = (const float*)d_in[16];
  const float* cs_w0  = (const float*)d_in[17];
  const float* cs_b0  = (const float*)d_in[18];
  const float* cs_w1  = (const float*)d_in[19];
  const float* cs_b1  = (const float*)d_in[20];
  const float* cs_w2  = (const float*)d_in[21];
  const float* cs_b2  = (const float*)d_in[22];
  const float* cs_w3  = (const float*)d_in[23];
  const float* cs_b3  = (const float*)d_in[24];

  float* out = (float*)d_out;
  float* o_feat   = out;                 // 4,194,304
  float* o_assign = out + 4194304;       // 16,384
  float* o_seg    = out + 4210688;       // 16,384
  float* o_out    = out + 4227072;       // 1,024 (B x 2)
  float* o_At     = out + 4228096;       // 16,384

  char* ws = (char*)d_ws;
  // conv phase
  unsigned short* WT = (unsigned short*)ws;             // [0, 12,582,912)
  float* PART  = (float*)(ws + 12582912);               // [12,582,912, 46,137,344)
  // post-conv phase (region A = dead WT)
  unsigned short* WVU = (unsigned short*)ws;            // 524,288 B
  unsigned short* WC0 = (unsigned short*)(ws + 524288); // 294,912 B
  unsigned short* WC1 = (unsigned short*)(ws + 819200); // 131,072 B
  float* AWS   = (float*)(ws + 950272);                 // 64 KB
  float* BAG   = (float*)(ws + 1015808);                // 512 KB
  float* BH0   = (float*)(ws + 1540096);                // 512 KB
  float* BH1   = (float*)(ws + 2064384);                // 256 KB
  float* BH2   = (float*)(ws + 2326528);                // 64 KB (ends 2,392,064)
  // region B = dead PART
  float* Y     = (float*)(ws + 12582912);               // 16384 x 512 = 33.55 MB
  float* SH0   = (float*)(ws + 12582912);               // 16.8 MB (after Y dead)
  float* SH1   = (float*)(ws + 29360128);               // 8.4 MB
  float* SH2   = (float*)(ws + 37748736);               // 2.1 MB (ends 39,845,888)

  // 1) conv weight repack + conv + reduce
  repack_frag_k<<<dim3(12288), dim3(256), 0, stream>>>(tsn_w, WT);
  conv_mfma_k<<<dim3(128, 2, 2), dim3(256), 0, stream>>>(x, WT, PART);
  reduce_bias_k<<<dim3(4096), dim3(256), 0, stream>>>(PART, tsn_b, o_feat);
  // 2) dense weight repacks (WT region is dead now)
  repack_dense_k<<<dim3(512), dim3(256), 0, stream>>>(aV_w, aU_w, 256, 256, 256, 32, WVU, 131072);
  repack_dense_k<<<dim3(288), dim3(256), 0, stream>>>(cs_w0, cs_w0, 256, 257, 257, 16, WC0, 73728);
  repack_dense_k<<<dim3(128), dim3(256), 0, stream>>>(cs_w1, cs_w1, 256, 256, 256, 8, WC1, 32768);
  // 3) fused aV|aU projection -> Y [16384 x 512]
  mfma_gemm_k<0,0><<<dim3(128, 4), dim3(256), 0, stream>>>(o_feat, 256, nullptr, WVU,
      131072, 32, 8, aV_b, aU_b, 256, Y, 512);
  // 4) gate -> AWS, o_At
  gate_k<<<dim3(4096), dim3(256), 0, stream>>>(Y, gate_w, gate_b, AWS, o_At);
  // 5) softmax + bag
  softmax_bag_k<<<dim3(512), dim3(256), 0, stream>>>(AWS, o_feat, BAG);
  // 6) bag classifier -> o_out[:,0]
  gemm_wt_k<1><<<dim3(4, 2), dim3(256), 0, stream>>>(BAG, 256, cb_w0, 256, 256, cb_b0, BH0, 256, 256);
  gemm_wt_k<1><<<dim3(4, 1), dim3(256), 0, stream>>>(BH0, 256, cb_w1, 256, 256, cb_b1, BH1, 128, 256);
  gemm_wt_k<1><<<dim3(4, 1), dim3(256), 0, stream>>>(BH1, 128, cb_w2, 128, 128, cb_b2, BH2, 32, 128);
  rowdot32_k<<<dim3(2), dim3(256), 0, stream>>>(BH2, cb_w3, cb_b3, o_out, 2, 0.5f);
  // 7) seg classifier (concat fused into A-stage) -> o_seg
  mfma_gemm_k<1,1><<<dim3(128, 2), dim3(256), 0, stream>>>(o_feat, 256, AWS, WC0,
      73728, 16, 9, cs_b0, cs_b0, 256, SH0, 256);
  mfma_gemm_k<1,0><<<dim3(128, 1), dim3(256), 0, stream>>>(SH0, 256, nullptr, WC1,
      32768, 8, 8, cs_b1, cs_b1, 128, SH1, 128);
  gemm_wt_k<1><<<dim3(128, 1), dim3(256), 0, stream>>>(SH1, 128, cs_w2, 128, 128, cs_b2, SH2, 32, 128);
  rowdot32_k<<<dim3(64), dim3(256), 0, stream>>>(SH2, cs_w3, cs_b3, o_seg, 1, 1.0f);
  // 8) kmeans -> assigns + o_out[:,1]
  kmeans_k<<<dim3(512), dim3(64), 0, stream>>>(o_feat, o_seg, o_assign, o_out);
}